// Round 5
// baseline (473.062 us; speedup 1.0000x reference)
//
#include <hip/hip_runtime.h>

#define NUM_C 19
#define HW_SHIFT 19                 // H*W = 512*1024 = 2^19
#define HW (1 << HW_SHIFT)          // 524288
#define NPIX (8 * HW)               // B*H*W = 4194304
#define BLOCK 256
#define GRID 1024                   // 4096 px/block, 16 px/thread, whole grid co-resident
#define SLOTS 40                    // 19 nll-sums + 19 counts + 2 pad (160 B aligned)

typedef float f32x4 __attribute__((ext_vector_type(4)));
typedef int   i32x4 __attribute__((ext_vector_type(4)));

// Model (r0-r4): total = F(~380 us: 1.245GB ws-poison fill 193 + harness restore
// ~185 + final 2) + main. r3 double-launch probe: main = 72.3 us (~4.7 TB/s read)
// for BOTH the batch-19-load and online-LSE forms; BW floor = 335.5MB/6.5TB/s = 52.
// Theory this round: reads cap at 4.7 because each wave interleaves 19 streams at
// 2MB power-of-2 stride in 1KB chunks -> DRAM row-buffer thrash (fill = 1 stream/CU
// at 6.5). Fix: 4KB contiguous per plane-visit per wave (4 back-to-back dwordx4),
// whole-grid-resident launch, non-temporal loads (pure stream, zero reuse).
__global__ __launch_bounds__(BLOCK) void ifl_main(const float* __restrict__ x,
                                                  const int* __restrict__ tgt,
                                                  float* __restrict__ part) {
    const int pixBlock = blockIdx.x << 12;           // 4096 px per block
    const int b  = pixBlock >> HW_SHIFT;             // batch, constant per block
    const int wv = threadIdx.x >> 6;
    const int ln = threadIdx.x & 63;
    // wave wv covers 1024 px; load j covers px [j*256, j*256+256) lane-contiguous
    const int roff = (pixBlock & (HW - 1)) + (wv << 10) + (ln << 2);
    const float* base = x + (((size_t)b * NUM_C) << HW_SHIFT) + roff;
    const int pix0 = pixBlock + (wv << 10) + (ln << 2);

    i32x4 tg[4];
#pragma unroll
    for (int j = 0; j < 4; ++j)
        tg[j] = __builtin_nontemporal_load(
            reinterpret_cast<const i32x4*>(tgt + pix0 + j * 256));

    float s[4][4], xt[4][4];
#pragma unroll
    for (int j = 0; j < 4; ++j)
#pragma unroll
        for (int k = 0; k < 4; ++k) { s[j][k] = 0.0f; xt[j][k] = 0.0f; }

    // online no-max LSE: logits are N(0,1) (|x|<~6), exp() safe unshifted
    // (absmax=0 verified r1-r3)
#pragma unroll
    for (int c = 0; c < NUM_C; ++c) {
        const float* pc = base + ((size_t)c << HW_SHIFT);
        f32x4 v[4];
#pragma unroll
        for (int j = 0; j < 4; ++j)   // 4 x 1KB wave-loads = 4KB contiguous run
            v[j] = __builtin_nontemporal_load(
                reinterpret_cast<const f32x4*>(pc + j * 256));
#pragma unroll
        for (int j = 0; j < 4; ++j)
#pragma unroll
            for (int k = 0; k < 4; ++k) {
                s[j][k] += __expf(v[j][k]);
                xt[j][k] = (tg[j][k] == c) ? v[j][k] : xt[j][k];
            }
    }

    // per-thread register histogram over the 16 pixels
    float acc[NUM_C], cnt[NUM_C];
#pragma unroll
    for (int c = 0; c < NUM_C; ++c) { acc[c] = 0.0f; cnt[c] = 0.0f; }
#pragma unroll
    for (int j = 0; j < 4; ++j)
#pragma unroll
        for (int k = 0; k < 4; ++k) {
            const float nll = __logf(s[j][k]) - xt[j][k];
            const int t = tg[j][k];
#pragma unroll
            for (int c = 0; c < NUM_C; ++c) {
                const bool h = (t == c);
                acc[c] += h ? nll : 0.0f;
                cnt[c] += h ? 1.0f : 0.0f;
            }
        }

    // wave(64) shuffle reduction -> LDS -> one partial store per block
    __shared__ float red[SLOTS];
    if (threadIdx.x < SLOTS) red[threadIdx.x] = 0.0f;
    __syncthreads();

#pragma unroll
    for (int c = 0; c < NUM_C; ++c) {
        float a = acc[c];
        float n = cnt[c];
#pragma unroll
        for (int off = 32; off > 0; off >>= 1) {
            a += __shfl_down(a, off, 64);
            n += __shfl_down(n, off, 64);
        }
        if ((threadIdx.x & 63) == 0) {
            atomicAdd(&red[c], a);            // <=4 colliding lanes (4 waves/block)
            atomicAdd(&red[NUM_C + c], n);
        }
    }
    __syncthreads();
    if (threadIdx.x < SLOTS) part[blockIdx.x * SLOTS + threadIdx.x] = red[threadIdx.x];
}

// Single block: reduce 1024x40 partials (~160 KB) and emit the weighted mean.
__global__ __launch_bounds__(BLOCK) void ifl_final(const float* __restrict__ part,
                                                   float* __restrict__ out) {
    __shared__ float red[SLOTS];
    if (threadIdx.x < SLOTS) red[threadIdx.x] = 0.0f;
    __syncthreads();

    float acc[SLOTS];
#pragma unroll
    for (int s = 0; s < SLOTS; ++s) acc[s] = 0.0f;

    for (int k = threadIdx.x; k < GRID; k += BLOCK) {
        const float4* p4 = reinterpret_cast<const float4*>(part + (size_t)k * SLOTS);
#pragma unroll
        for (int q = 0; q < SLOTS / 4; ++q) {
            const float4 v = p4[q];
            acc[4 * q + 0] += v.x;
            acc[4 * q + 1] += v.y;
            acc[4 * q + 2] += v.z;
            acc[4 * q + 3] += v.w;
        }
    }

#pragma unroll
    for (int s = 0; s < SLOTS; ++s) {
        float v = acc[s];
#pragma unroll
        for (int off = 32; off > 0; off >>= 1) v += __shfl_down(v, off, 64);
        if ((threadIdx.x & 63) == 0) atomicAdd(&red[s], v);
    }
    __syncthreads();

    if (threadIdx.x == 0) {
        float num = 0.f, den = 0.f;
#pragma unroll
        for (int c = 0; c < NUM_C; ++c) {
            const float cn = red[NUM_C + c];
            const float inv = (cn > 0.f) ? (1.f / fmaxf(cn, 1.f)) : 1.f;
            num += inv * red[c];
            den += inv * cn;
        }
        out[0] = num / den;
    }
}

extern "C" void kernel_launch(void* const* d_in, const int* in_sizes, int n_in,
                              void* d_out, int out_size, void* d_ws, size_t ws_size,
                              hipStream_t stream) {
    const float* x = (const float*)d_in[0];
    const int* tgt = (const int*)d_in[1];
    float* ws = (float*)d_ws;
    float* out = (float*)d_out;

    ifl_main<<<GRID, BLOCK, 0, stream>>>(x, tgt, ws);
    ifl_final<<<1, BLOCK, 0, stream>>>(ws, out);
}

// Round 6
// 449.365 us; speedup vs baseline: 1.0527x; 1.0527x over previous
//
#include <hip/hip_runtime.h>

#define NUM_C 19
#define HW_SHIFT 19                 // H*W = 512*1024 = 2^19
#define HW (1 << HW_SHIFT)          // 524288
#define NPIX (8 * HW)               // B*H*W = 4194304
#define NGROUPS (NPIX / 4)          // float4 groups = 1048576
#define BLOCK 256
#define GRID 2048
#define NTH (GRID * BLOCK)          // 524288 -> exactly 2 unrolled iterations
#define SLOTS 40                    // 19 nll-sums + 19 counts + 2 pad (160 B, float4-aligned)

// REVERT to the measured-best r4 kernel (451.8 us; main = 72.3 us by the r3
// double-launch probe). Session evidence: four structurally distinct mains all
// land at 72+-1 us (~4.7 TB/s on the 19-stream 2MB-stride read); both directed
// restructurings (stride-32 r1, 4KB-runs+nt+16px/thread r5) regressed. Total =
// F(~380 us harness: 1.245GB ws-poison fill 193 + restore ~185) + main 72 + final 2.
__global__ __launch_bounds__(BLOCK) void ifl_main(const float* __restrict__ x,
                                                  const int* __restrict__ tgt,
                                                  float* __restrict__ part) {
    float acc[NUM_C], cnt[NUM_C];
#pragma unroll
    for (int c = 0; c < NUM_C; ++c) { acc[c] = 0.0f; cnt[c] = 0.0f; }

    const int tid = blockIdx.x * BLOCK + threadIdx.x;

    union F4 { float4 q; float f[4]; };
    union I4 { int4 q; int i[4]; };

#pragma unroll
    for (int it = 0; it < NGROUPS / NTH; ++it) {
        const int g = tid + it * NTH;           // lane-contiguous float4 groups
        const int p = g << 2;                   // pixel index (4-aligned, never crosses batch)
        const int b = p >> HW_SHIFT;
        const int r = p & (HW - 1);
        const float4* base4 =
            reinterpret_cast<const float4*>(x + (((size_t)b * NUM_C) << HW_SHIFT) + r);

        // batch all 19 plane loads first: 19 outstanding dwordx4/lane (deep MLP)
        F4 v[NUM_C];
#pragma unroll
        for (int c = 0; c < NUM_C; ++c) v[c].q = base4[(size_t)c << (HW_SHIFT - 2)];

        I4 tt;
        tt.q = *reinterpret_cast<const int4*>(tgt + p);

#pragma unroll
        for (int k = 0; k < 4; ++k) {
            const int tg = tt.i[k];
            float m = v[0].f[k];
#pragma unroll
            for (int c = 1; c < NUM_C; ++c) m = fmaxf(m, v[c].f[k]);
            float s = 0.0f;
#pragma unroll
            for (int c = 0; c < NUM_C; ++c) s += __expf(v[c].f[k] - m);
            float xt = v[0].f[k];
#pragma unroll
            for (int c = 1; c < NUM_C; ++c) xt = (tg == c) ? v[c].f[k] : xt;
            const float nll = m + __logf(s) - xt;
#pragma unroll
            for (int c = 0; c < NUM_C; ++c) {
                const bool h = (tg == c);
                acc[c] += h ? nll : 0.0f;
                cnt[c] += h ? 1.0f : 0.0f;
            }
        }
    }

    // wave(64) shuffle reduction -> LDS -> one partial store per block
    __shared__ float red[SLOTS];
    if (threadIdx.x < SLOTS) red[threadIdx.x] = 0.0f;
    __syncthreads();

#pragma unroll
    for (int c = 0; c < NUM_C; ++c) {
        float a = acc[c];
        float n = cnt[c];
#pragma unroll
        for (int off = 32; off > 0; off >>= 1) {
            a += __shfl_down(a, off, 64);
            n += __shfl_down(n, off, 64);
        }
        if ((threadIdx.x & 63) == 0) {
            atomicAdd(&red[c], a);            // <=4 colliding lanes (4 waves/block)
            atomicAdd(&red[NUM_C + c], n);
        }
    }
    __syncthreads();
    if (threadIdx.x < SLOTS) part[blockIdx.x * SLOTS + threadIdx.x] = red[threadIdx.x];
}

// Single block: reduce 2048x40 partials (~320 KB) and emit the weighted mean.
__global__ __launch_bounds__(BLOCK) void ifl_final(const float* __restrict__ part,
                                                   float* __restrict__ out) {
    __shared__ float red[SLOTS];
    if (threadIdx.x < SLOTS) red[threadIdx.x] = 0.0f;
    __syncthreads();

    float acc[SLOTS];
#pragma unroll
    for (int s = 0; s < SLOTS; ++s) acc[s] = 0.0f;

    for (int k = threadIdx.x; k < GRID; k += BLOCK) {
        const float4* p4 = reinterpret_cast<const float4*>(part + (size_t)k * SLOTS);
#pragma unroll
        for (int q = 0; q < SLOTS / 4; ++q) {
            const float4 v = p4[q];
            acc[4 * q + 0] += v.x;
            acc[4 * q + 1] += v.y;
            acc[4 * q + 2] += v.z;
            acc[4 * q + 3] += v.w;
        }
    }

#pragma unroll
    for (int s = 0; s < SLOTS; ++s) {
        float v = acc[s];
#pragma unroll
        for (int off = 32; off > 0; off >>= 1) v += __shfl_down(v, off, 64);
        if ((threadIdx.x & 63) == 0) atomicAdd(&red[s], v);
    }
    __syncthreads();

    if (threadIdx.x == 0) {
        float num = 0.f, den = 0.f;
#pragma unroll
        for (int c = 0; c < NUM_C; ++c) {
            const float cn = red[NUM_C + c];
            const float inv = (cn > 0.f) ? (1.f / fmaxf(cn, 1.f)) : 1.f;
            num += inv * red[c];
            den += inv * cn;
        }
        out[0] = num / den;
    }
}

extern "C" void kernel_launch(void* const* d_in, const int* in_sizes, int n_in,
                              void* d_out, int out_size, void* d_ws, size_t ws_size,
                              hipStream_t stream) {
    const float* x = (const float*)d_in[0];
    const int* tgt = (const int*)d_in[1];
    float* ws = (float*)d_ws;
    float* out = (float*)d_out;

    ifl_main<<<GRID, BLOCK, 0, stream>>>(x, tgt, ws);
    ifl_final<<<1, BLOCK, 0, stream>>>(ws, out);
}